// Round 4
// baseline (18065.916 us; speedup 1.0000x reference)
//
#include <hip/hip_runtime.h>

#define TT 8192
#define HH 200
#define NPB 25      // neurons per recurrence block (8 blocks/layer)
#define RD 1024     // pre1 ring depth (steps)
#define RDM 1023
#define BPWIN 900   // backpressure window (< RD - prog staleness)

typedef unsigned long long u64;
typedef unsigned int u32;

__device__ __forceinline__ float sigmoidf_(float x){ return 1.0f/(1.0f+__expf(-x)); }
__device__ __forceinline__ float tanhf_(float x){
    float e = __expf(2.0f*fabsf(x));
    float r = 1.0f - 2.0f/(e + 1.0f);
    return copysignf(r, x);
}
__device__ __forceinline__ u64 pck(u32 tag, float v){
    return ((u64)tag << 32) | (u64)__float_as_uint(v);
}
__device__ __forceinline__ u64 ald(const u64* p){
    return __hip_atomic_load((u64*)p, __ATOMIC_RELAXED, __HIP_MEMORY_SCOPE_AGENT);
}
__device__ __forceinline__ void ast(u64* p, u64 v){
    __hip_atomic_store(p, v, __ATOMIC_RELAXED, __HIP_MEMORY_SCOPE_AGENT);
}

// 64 lanes (m) fetch 200 tagged values into dst (loads batched in flight)
__device__ __forceinline__ void poll200(const u64* base, u32 tag, float* dst, int m){
    u64 v0, v1, v2, v3 = 0;
    const bool g3 = (m < 8);
    for(;;){
        v0 = ald(base + m);
        v1 = ald(base + m + 64);
        v2 = ald(base + m + 128);
        if (g3) v3 = ald(base + m + 192);
        if ((u32)(v0>>32)==tag && (u32)(v1>>32)==tag && (u32)(v2>>32)==tag &&
            (!g3 || (u32)(v3>>32)==tag)) break;
    }
    dst[m]       = __uint_as_float((u32)v0);
    dst[m + 64]  = __uint_as_float((u32)v1);
    dst[m + 128] = __uint_as_float((u32)v2);
    if (g3) dst[m + 192] = __uint_as_float((u32)v3);
}

// 64 lanes (m) fetch the 175 REMOTE tagged values (skip own [nb,nb+25))
__device__ __forceinline__ void poll175(const u64* base, u32 tag, float* dst,
                                        int m, int nb){
    const int m2 = m + 128;
    const bool g2 = (m2 < 175);
    const int i0 = m      + (m      >= nb ? NPB : 0);
    const int i1 = m + 64 + (m + 64 >= nb ? NPB : 0);
    const int i2 = g2 ? (m2 + (m2 >= nb ? NPB : 0)) : 0;
    u64 v0, v1, v2 = 0;
    for(;;){
        v0 = ald(base + i0);
        v1 = ald(base + i1);
        if (g2) v2 = ald(base + i2);
        if ((u32)(v0>>32)==tag && (u32)(v1>>32)==tag &&
            (!g2 || (u32)(v2>>32)==tag)) break;
    }
    dst[i0] = __uint_as_float((u32)v0);
    dst[i1] = __uint_as_float((u32)v1);
    if (g2) dst[i2] = __uint_as_float((u32)v2);
}

// 48 lanes (m) fetch this block's 100 pre1 rows from a ring slot
__device__ __forceinline__ void pollP(const u64* slot, u32 tag, float* dst,
                                      int m, int nb){
    const int mm0 = m, mm1 = m + 48, mm2 = m + 96;
    const int i0 = (mm0/NPB)*HH + nb + mm0%NPB;
    const int i1 = (mm1/NPB)*HH + nb + mm1%NPB;
    const bool g2 = (mm2 < 100);
    const int i2 = g2 ? (mm2/NPB)*HH + nb + mm2%NPB : 0;
    u64 v0, v1, v2 = 0;
    for(;;){
        v0 = ald(slot + i0);
        v1 = ald(slot + i1);
        if (g2) v2 = ald(slot + i2);
        if ((u32)(v0>>32)==tag && (u32)(v1>>32)==tag &&
            (!g2 || (u32)(v2>>32)==tag)) break;
    }
    dst[mm0] = __uint_as_float((u32)v0);
    dst[mm1] = __uint_as_float((u32)v1);
    if (g2) dst[mm2] = __uint_as_float((u32)v2);
}

// roles: 0-7 layer-0 recurrence, 8-15 pre1 stream, 16-23 layer-1 recurrence.
// 100 gate rows/block (4 gates x 25 neurons), 4 lanes/row (K=50, w[50]
// PINNED in VGPRs via asm black-box), shfl_xor reduce, tagged-atomic exchange.
__global__ __launch_bounds__(512, 1)
void lstm_pipe(const float* __restrict__ x,
               const float* __restrict__ Wih0, const float* __restrict__ Whh0,
               const float* __restrict__ bih0, const float* __restrict__ bhh0,
               const float* __restrict__ Wih1, const float* __restrict__ Whh1,
               const float* __restrict__ bih1, const float* __restrict__ bhh1,
               const float* __restrict__ Wout, const float* __restrict__ bout,
               u64* __restrict__ h0s,   // [TT][HH] tagged
               u64* __restrict__ p1r,   // [RD][800] tagged ring
               u64* __restrict__ h1x,   // [64][HH] tagged ring
               u32* __restrict__ prog,  // [1] layer-1 progress
               float* __restrict__ out)
{
    const int role = blockIdx.x;
    const int tid  = threadIdx.x;

    __shared__ float xs[TT];          // 32 KB (L0 roles only)
    __shared__ float h_lds[2][HH];    // pre1: double buffer; recurrence: [0]
    __shared__ float s_lds[100];
    __shared__ float p_lds[2][100];   // L1 only

    const int lg = tid >> 2;          // row 0..127 (100 used)
    const int kq = tid & 3;           // K-quarter
    const bool fa = (tid < 400);

    // ---------------- pre1 streaming stage ----------------
    if (role >= 8 && role < 16) {
        const int nb = (role - 8) * NPB;
        int grow = 0; float bs = 0.f;
        float w[50];
        if (fa) {
            const int q = lg / NPB, j = lg % NPB;
            grow = q * HH + nb + j;
            const float* wr = Wih1 + (size_t)grow * HH + kq * 50;
            #pragma unroll
            for (int k = 0; k < 50; ++k) w[k] = wr[k];
            #pragma unroll
            for (int k = 0; k < 50; ++k) asm volatile("" : "+v"(w[k]));
            if (kq == 0) {
                bs = bih1[grow] + bhh1[grow];
                asm volatile("" : "+v"(bs));
            }
        }
        u32 prog_c = 0;
        if (tid >= 448)                       // preload h0[0]
            poll200(h0s, 1u, h_lds[0], tid - 448);
        __syncthreads();
        for (int t = 0; t < TT; ++t) {
            const int p = t & 1;
            if (fa) {
                float a0 = 0.f, a1 = 0.f;
                const float2* h2 = (const float2*)(h_lds[p] + kq * 50);
                #pragma unroll
                for (int m2 = 0; m2 < 25; ++m2) {
                    float2 hv = h2[m2];
                    a0 += w[2*m2]   * hv.x;
                    a1 += w[2*m2+1] * hv.y;
                }
                float s = a0 + a1;
                s += __shfl_xor(s, 1);
                s += __shfl_xor(s, 2);
                if (kq == 0)
                    ast(&p1r[(size_t)(t & RDM) * 800 + grow],
                        pck((u32)(t + 1), s + bs));
            } else if (tid >= 448) {          // prefetch h0[t+1]
                if (t + 1 < TT)
                    poll200(&h0s[(size_t)(t+1) * HH], (u32)(t + 2),
                            h_lds[p ^ 1], tid - 448);
            } else if (tid == 400) {          // ring backpressure
                while ((int)(t + 1) - (int)prog_c >= BPWIN) {
                    __builtin_amdgcn_s_sleep(8);
                    prog_c = __hip_atomic_load(prog, __ATOMIC_RELAXED,
                                               __HIP_MEMORY_SCOPE_AGENT);
                }
            }
            __syncthreads();
        }
        return;
    }

    // ---------------- recurrence stages ----------------
    const bool L0 = (role < 8);
    const int b  = L0 ? role : role - 16;
    const int nb = b * NPB;
    const float* Whh = L0 ? Whh0 : Whh1;

    int grow = 0; float wih = 0.f, bs = 0.f;
    float w[50];
    if (fa) {
        const int q = lg / NPB, j = lg % NPB;
        grow = q * HH + nb + j;
        const float* wr = Whh + (size_t)grow * HH + kq * 50;
        #pragma unroll
        for (int k = 0; k < 50; ++k) w[k] = wr[k];
        #pragma unroll
        for (int k = 0; k < 50; ++k) asm volatile("" : "+v"(w[k]));
        if (L0 && kq == 0) {
            bs = bih0[grow] + bhh0[grow]; wih = Wih0[grow];
            asm volatile("" : "+v"(bs));
            asm volatile("" : "+v"(wih));
        }
    }
    if (L0) for (int i = tid; i < TT; i += 512) xs[i] = x[i];
    if (tid < HH) h_lds[0][tid] = 0.f;

    if (!L0 && tid >= 400 && tid < 448)       // preload pre1[0]
        pollP(p1r, 1u, p_lds[0], tid - 400, nb);

    float c = 0.f;
    __syncthreads();

    for (int t = 0; t < TT; ++t) {
        // ---- phase A: FMA on h[t-1]; L1 lanes 400-447 prefetch pre1[t+1] ----
        if (fa) {
            float a0 = 0.f, a1 = 0.f;
            const float2* h2 = (const float2*)(h_lds[0] + kq * 50);
            #pragma unroll
            for (int m2 = 0; m2 < 25; ++m2) {
                float2 hv = h2[m2];
                a0 += w[2*m2]   * hv.x;
                a1 += w[2*m2+1] * hv.y;
            }
            float s = a0 + a1;
            s += __shfl_xor(s, 1);
            s += __shfl_xor(s, 2);
            if (kq == 0) {
                if (L0) s_lds[lg] = s + xs[t] * wih + bs;
                else    s_lds[lg] = s + p_lds[t & 1][lg];
            }
        } else if (!L0 && tid < 448) {
            if (t + 1 < TT)
                pollP(&p1r[(size_t)((t + 1) & RDM) * 800], (u32)(t + 2),
                      p_lds[(t + 1) & 1], tid - 400, nb);
        }
        __syncthreads();
        // ---- phase B: gates (lanes<25, own-h direct to LDS) || poll 175 ----
        if (tid < NPB) {
            float ig = sigmoidf_(s_lds[tid]);
            float fg = sigmoidf_(s_lds[NPB + tid]);
            float gg = tanhf_  (s_lds[2*NPB + tid]);
            float og = sigmoidf_(s_lds[3*NPB + tid]);
            c = fg * c + ig * gg;
            float h = og * tanhf_(c);
            h_lds[0][nb + tid] = h;           // own chunk: no MALL round-trip
            if (L0) ast(&h0s[(size_t)t * HH + nb + tid], pck((u32)(t+1), h));
            else    ast(&h1x[(size_t)(t & 63) * HH + nb + tid], pck((u32)(t+1), h));
        } else if (tid >= 448) {
            const u64* base = L0 ? &h0s[(size_t)t * HH]
                                 : &h1x[(size_t)(t & 63) * HH];
            poll175(base, (u32)(t + 1), h_lds[0], tid - 448, nb);
        } else if (!L0 && b == 0 && tid == 32 && (t & 63) == 63) {
            __hip_atomic_store(prog, (u32)(t + 1), __ATOMIC_RELAXED,
                               __HIP_MEMORY_SCOPE_AGENT);
        }
        __syncthreads();
    }

    // ---- linear head on final h1 (L1 block 0) ----
    if (!L0 && b == 0 && tid < 64) {
        float s2 = 0.f;
        for (int k = tid; k < HH; k += 64) s2 += h_lds[0][k] * Wout[k];
        #pragma unroll
        for (int off = 32; off > 0; off >>= 1) s2 += __shfl_down(s2, off);
        if (tid == 0) out[0] = s2 + bout[0];
    }
}

extern "C" void kernel_launch(void* const* d_in, const int* in_sizes, int n_in,
                              void* d_out, int out_size, void* d_ws, size_t ws_size,
                              hipStream_t stream) {
    const float* x    = (const float*)d_in[0];
    const float* Wih0 = (const float*)d_in[1];
    const float* Whh0 = (const float*)d_in[2];
    const float* bih0 = (const float*)d_in[3];
    const float* bhh0 = (const float*)d_in[4];
    const float* Wih1 = (const float*)d_in[5];
    const float* Whh1 = (const float*)d_in[6];
    const float* bih1 = (const float*)d_in[7];
    const float* bhh1 = (const float*)d_in[8];
    const float* Wout = (const float*)d_in[9];
    const float* bout = (const float*)d_in[10];
    float* out = (float*)d_out;

    char* ws = (char*)d_ws;
    // h0s 13,107,200 | p1r 6,553,600 | h1x 102,400 | prog 64
    u64* h0s  = (u64*)ws;
    u64* p1r  = (u64*)(ws + 13107200);
    u64* h1x  = (u64*)(ws + 19660800);
    u32* prog = (u32*)(ws + 19763200);

    // clear all tags/progress every launch (graph-safe, deterministic)
    hipMemsetAsync(ws, 0, 19763264, stream);

    hipLaunchKernelGGL(lstm_pipe, dim3(24), dim3(512), 0, stream,
        x, Wih0, Whh0, bih0, bhh0, Wih1, Whh1, bih1, bhh1, Wout, bout,
        h0s, p1r, h1x, prog, out);
}